// Round 12
// baseline (266.168 us; speedup 1.0000x reference)
//
#include <hip/hip_runtime.h>
#include <hip/hip_bf16.h>

typedef __bf16 bf16;
typedef bf16 bf16x8 __attribute__((ext_vector_type(8)));
typedef bf16 bf16x4 __attribute__((ext_vector_type(4)));
typedef float f32x4 __attribute__((ext_vector_type(4)));

static constexpr int SEQ    = 4096;
static constexpr int DMODEL = 1024;
static constexpr int NHEADS = 16;
static constexpr int DHEAD  = 64;
static constexpr int QKV3   = 3 * DMODEL;  // 3072
static constexpr float SMAX = 64.0f;       // Cauchy-Schwarz bound on q.k after rmsnorm

// Async global->LDS 16B copy. LDS dest must be wave-uniform base + lane*16.
__device__ inline void gld16(const bf16* g, bf16* l) {
    __builtin_amdgcn_global_load_lds(
        (const __attribute__((address_space(1))) void*)g,
        (__attribute__((address_space(3))) void*)l, 16, 0, 0);
}

__device__ inline bf16x8 load8(const float* src) {
    float4 a = *(const float4*)(src);
    float4 b = *(const float4*)(src + 4);
    bf16x8 r;
    r[0] = (bf16)a.x; r[1] = (bf16)a.y; r[2] = (bf16)a.z; r[3] = (bf16)a.w;
    r[4] = (bf16)b.x; r[5] = (bf16)b.y; r[6] = (bf16)b.z; r[7] = (bf16)b.w;
    return r;
}

// ---------------------------------------------------------------------------
// One fused fp32->bf16 convert over x | Wqkv | Wo (outputs adjacent in ws).
// ---------------------------------------------------------------------------
static constexpr size_t NX = (size_t)SEQ * DMODEL;     // 4194304
static constexpr size_t NW = (size_t)QKV3 * DMODEL;    // 3145728
static constexpr size_t NO = (size_t)DMODEL * DMODEL;  // 1048576

__global__ __launch_bounds__(256)
void cvt_all(const float* __restrict__ x, const float* __restrict__ Wqkv,
             const float* __restrict__ Wo, bf16* __restrict__ outbase) {
    const size_t e = ((size_t)blockIdx.x * 256 + threadIdx.x) * 8;
    const float* src;
    if (e < NX)            src = x + e;
    else if (e < NX + NW)  src = Wqkv + (e - NX);
    else                   src = Wo + (e - NX - NW);
    *(bf16x8*)(outbase + e) = load8(src);
}

// ---------------------------------------------------------------------------
// QKV GEMM with fused per-head RMSNorm (q,k) and fused V-transpose.
// R12 change: epilogue routes through a per-wave LDS tile (64x72) and writes
// out fully coalesced (16B/lane), killing the 8B-stride-8KB scatter that
// caused ~16x HBM write amplification in R11. Values bit-identical to R11.
// ---------------------------------------------------------------------------
__global__ __launch_bounds__(256)
void gemm_qkv(const bf16* __restrict__ A, const bf16* __restrict__ W,
              const float* __restrict__ bias, const float* __restrict__ wq,
              const float* __restrict__ wk, bf16* __restrict__ qkv,
              bf16* __restrict__ Vt) {
    __shared__ __align__(16) bf16 As[128 * 32];
    __shared__ __align__(16) bf16 Ws[128 * 32];
    __shared__ __align__(16) bf16 epi[4][64 * 72];   // per-wave epilogue tile
    const int tid  = threadIdx.x;
    const int wave = tid >> 6;
    const int lane = tid & 63;
    const int ll   = tid & 15;
    const int quad = (tid & 63) >> 4;
    const int wm   = (wave >> 1) * 64;
    const int wn   = (wave & 1) * 64;
    const int m0 = blockIdx.y * 128;
    const int n0 = blockIdx.x * 128;

    f32x4 acc[4][4];
#pragma unroll
    for (int i = 0; i < 4; ++i)
#pragma unroll
        for (int j = 0; j < 4; ++j) acc[i][j] = (f32x4){0.f, 0.f, 0.f, 0.f};

    for (int k0 = 0; k0 < DMODEL; k0 += 32) {
        __syncthreads();
#pragma unroll
        for (int i = 0; i < 2; ++i) {
            const int idx = i * 256 + tid;
            const int row = idx >> 2;
            const int c   = (idx & 3) ^ ((row >> 1) & 3);
            gld16(&A[(size_t)(m0 + row) * DMODEL + k0 + c * 8], As + idx * 8);
            gld16(&W[(size_t)(n0 + row) * DMODEL + k0 + c * 8], Ws + idx * 8);
        }
        __syncthreads();
        bf16x8 af[4], bfr[4];
#pragma unroll
        for (int mi = 0; mi < 4; ++mi) {
            const int row = wm + mi * 16 + ll;
            af[mi] = *(const bf16x8*)(As + (row * 4 + (quad ^ ((ll >> 1) & 3))) * 8);
        }
#pragma unroll
        for (int ni = 0; ni < 4; ++ni) {
            const int row = wn + ni * 16 + ll;
            bfr[ni] = *(const bf16x8*)(Ws + (row * 4 + (quad ^ ((ll >> 1) & 3))) * 8);
        }
#pragma unroll
        for (int mi = 0; mi < 4; ++mi)
#pragma unroll
            for (int ni = 0; ni < 4; ++ni)
                acc[mi][ni] = __builtin_amdgcn_mfma_f32_16x16x32_bf16(
                    af[mi], bfr[ni], acc[mi][ni], 0, 0, 0);
    }

    float bvn[4];
#pragma unroll
    for (int ni = 0; ni < 4; ++ni) bvn[ni] = bias[n0 + wn + ni * 16 + ll];

    bf16* et = epi[wave];
    const int sect = (n0 + wn) >> 10;      // 0=q, 1=k, 2=v (wave-uniform)
    if (sect < 2) {
        const float* wv = sect ? wk : wq;
        float wvl[4];
#pragma unroll
        for (int ni = 0; ni < 4; ++ni) wvl[ni] = wv[ni * 16 + ll];
#pragma unroll
        for (int mi = 0; mi < 4; ++mi)
#pragma unroll
            for (int r = 0; r < 4; ++r) {
                float xf[4];
                float ss = 0.f;
#pragma unroll
                for (int ni = 0; ni < 4; ++ni) {
                    xf[ni] = (float)(bf16)(acc[mi][ni][r] + bvn[ni]);
                    ss += xf[ni] * xf[ni];
                }
#pragma unroll
                for (int off = 1; off < 16; off <<= 1) ss += __shfl_xor(ss, off);
                const float scale = rsqrtf(ss * (1.0f / 64.0f) + 1e-6f);
                const int rl = mi * 16 + quad * 4 + r;   // local row 0..63
#pragma unroll
                for (int ni = 0; ni < 4; ++ni)
                    et[rl * 72 + ni * 16 + ll] = (bf16)(xf[ni] * scale * wvl[ni]);
            }
        // wave-local LDS tile -> coalesced 16B/lane stores (no barrier needed)
#pragma unroll
        for (int pass = 0; pass < 8; ++pass) {
            const int rl   = pass * 8 + (lane >> 3);
            const int col8 = (lane & 7) * 8;
            bf16x8 v = *(const bf16x8*)(et + rl * 72 + col8);
            *(bf16x8*)(qkv + (size_t)(m0 + wm + rl) * QKV3 + n0 + wn + col8) = v;
        }
    } else {
        const int h = (n0 + wn - 2 * DMODEL) >> 6;   // head (wave-uniform)
        // write transposed into LDS: epi[d_local][kv_local]
#pragma unroll
        for (int mi = 0; mi < 4; ++mi)
#pragma unroll
            for (int ni = 0; ni < 4; ++ni)
#pragma unroll
                for (int r = 0; r < 4; ++r)
                    et[(ni * 16 + ll) * 72 + mi * 16 + quad * 4 + r] =
                        (bf16)(acc[mi][ni][r] + bvn[ni]);
        // coalesced: each d-row is 64 kv * 2B = 128B = 8 lanes x 16B
#pragma unroll
        for (int pass = 0; pass < 8; ++pass) {
            const int dl   = pass * 8 + (lane >> 3);
            const int col8 = (lane & 7) * 8;
            bf16x8 v = *(const bf16x8*)(et + dl * 72 + col8);
            *(bf16x8*)(Vt + (size_t)(h * DHEAD + dl) * SEQ + m0 + wm + col8) = v;
        }
    }
}

// ---------------------------------------------------------------------------
// Output GEMM: out[M,1024] = z @ Wo^T + bo, fp32 out. 128x64 tile (R11).
// ---------------------------------------------------------------------------
__global__ __launch_bounds__(256)
void gemm_out(const bf16* __restrict__ A, const bf16* __restrict__ W,
              const float* __restrict__ bias, float* __restrict__ C) {
    __shared__ __align__(16) bf16 As[128 * 32];
    __shared__ __align__(16) bf16 Ws[64 * 32];
    const int tid  = threadIdx.x;
    const int wave = tid >> 6;
    const int ll   = tid & 15;
    const int quad = (tid & 63) >> 4;
    const int m0 = blockIdx.y * 128;
    const int n0 = blockIdx.x * 64;

    f32x4 acc[2][4];
#pragma unroll
    for (int i = 0; i < 2; ++i)
#pragma unroll
        for (int j = 0; j < 4; ++j) acc[i][j] = (f32x4){0.f, 0.f, 0.f, 0.f};

    for (int k0 = 0; k0 < DMODEL; k0 += 32) {
        __syncthreads();
#pragma unroll
        for (int i = 0; i < 2; ++i) {
            const int idx = i * 256 + tid;
            const int row = idx >> 2;
            const int c   = (idx & 3) ^ ((row >> 1) & 3);
            gld16(&A[(size_t)(m0 + row) * DMODEL + k0 + c * 8], As + idx * 8);
        }
        {
            const int j   = tid;
            const int row = j >> 2;
            const int c   = (j & 3) ^ ((row >> 1) & 3);
            gld16(&W[(size_t)(n0 + row) * DMODEL + k0 + c * 8], Ws + j * 8);
        }
        __syncthreads();
        bf16x8 af[2], bfr[4];
#pragma unroll
        for (int mi = 0; mi < 2; ++mi) {
            const int row = wave * 32 + mi * 16 + ll;
            af[mi] = *(const bf16x8*)(As + (row * 4 + (quad ^ ((ll >> 1) & 3))) * 8);
        }
#pragma unroll
        for (int ni = 0; ni < 4; ++ni) {
            const int row = ni * 16 + ll;
            bfr[ni] = *(const bf16x8*)(Ws + (row * 4 + (quad ^ ((ll >> 1) & 3))) * 8);
        }
#pragma unroll
        for (int mi = 0; mi < 2; ++mi)
#pragma unroll
            for (int ni = 0; ni < 4; ++ni)
                acc[mi][ni] = __builtin_amdgcn_mfma_f32_16x16x32_bf16(
                    af[mi], bfr[ni], acc[mi][ni], 0, 0, 0);
    }
#pragma unroll
    for (int ni = 0; ni < 4; ++ni) {
        const int col = n0 + ni * 16 + ll;
        const float bv = bias[col];
#pragma unroll
        for (int mi = 0; mi < 2; ++mi)
#pragma unroll
            for (int r = 0; r < 4; ++r) {
                const int row = m0 + wave * 32 + mi * 16 + quad * 4 + r;
                C[(size_t)row * DMODEL + col] = acc[mi][ni][r] + bv;
            }
    }
}

// ---------------------------------------------------------------------------
// Flash attention with fixed-max softmax (R10-proven, untouched).
// ---------------------------------------------------------------------------
template<bool PARTIAL>
__global__ __launch_bounds__(256, 4)
void attn_fwd(const bf16* __restrict__ qkv, const bf16* __restrict__ Vt,
              bf16* __restrict__ z, float* __restrict__ opf,
              float* __restrict__ lsum) {
    __shared__ __align__(16) bf16 Ks[64 * 64];
    __shared__ __align__(16) bf16 VTs[64 * 64];
    __shared__ __align__(16) bf16 Ps[128 * 72];   // also Q staging scratch

    const int tid  = threadIdx.x;
    const int wave = tid >> 6;
    const int ll   = tid & 15;
    const int quad = (tid & 63) >> 4;
    const int head = blockIdx.x;
    const int q0   = blockIdx.y * 128;
    const int half = PARTIAL ? blockIdx.z : 0;
    const int kvbeg = half * (SEQ / 2);
    const int kvlen = PARTIAL ? (SEQ / 2) : SEQ;
    const int wrow = wave * 32;

    const bf16* kbase  = qkv + DMODEL + head * DHEAD;
    const bf16* vtbase = Vt + (size_t)head * DHEAD * SEQ;

#pragma unroll
    for (int i = 0; i < 4; ++i) {
        const int idx = i * 256 + tid;
        const int row = idx >> 3;
        const int c   = (idx & 7) ^ (row & 7);
        gld16(qkv + (size_t)(q0 + row) * QKV3 + head * DHEAD + c * 8, Ps + idx * 8);
    }
    __syncthreads();
    bf16x8 aq[2][2];
#pragma unroll
    for (int sub = 0; sub < 2; ++sub)
#pragma unroll
        for (int ks = 0; ks < 2; ++ks) {
            const int row = wrow + sub * 16 + ll;
            const int pc  = (ks * 4 + quad) ^ (ll & 7);
            aq[sub][ks] = *(const bf16x8*)(Ps + (row * 8 + pc) * 8);
        }

    f32x4 lp[2];
    f32x4 o[2][4];
#pragma unroll
    for (int sub = 0; sub < 2; ++sub) {
        lp[sub] = (f32x4){0.f, 0.f, 0.f, 0.f};
#pragma unroll
        for (int nt = 0; nt < 4; ++nt) o[sub][nt] = (f32x4){0.f, 0.f, 0.f, 0.f};
    }

    for (int kv0 = kvbeg; kv0 < kvbeg + kvlen; kv0 += 64) {
        __syncthreads();
#pragma unroll
        for (int i = 0; i < 2; ++i) {
            const int idx = i * 256 + tid;
            const int row = idx >> 3;
            const int c   = (idx & 7) ^ (row & 7);
            gld16(kbase + (size_t)(kv0 + row) * QKV3 + c * 8, Ks + idx * 8);
            gld16(vtbase + (size_t)row * SEQ + kv0 + c * 8, VTs + idx * 8);
        }
        __syncthreads();

        f32x4 s[2][4];
#pragma unroll
        for (int nt = 0; nt < 4; ++nt) {
            s[0][nt] = (f32x4){0.f, 0.f, 0.f, 0.f};
            s[1][nt] = (f32x4){0.f, 0.f, 0.f, 0.f};
        }
#pragma unroll
        for (int ks = 0; ks < 2; ++ks)
#pragma unroll
            for (int nt = 0; nt < 4; ++nt) {
                const int row = nt * 16 + ll;
                const int pc  = (ks * 4 + quad) ^ (ll & 7);
                bf16x8 b = *(const bf16x8*)(Ks + (row * 8 + pc) * 8);
                s[0][nt] = __builtin_amdgcn_mfma_f32_16x16x32_bf16(aq[0][ks], b, s[0][nt], 0, 0, 0);
                s[1][nt] = __builtin_amdgcn_mfma_f32_16x16x32_bf16(aq[1][ks], b, s[1][nt], 0, 0, 0);
            }

#pragma unroll
        for (int sub = 0; sub < 2; ++sub) {
#pragma unroll
            for (int nt = 0; nt < 4; ++nt)
#pragma unroll
                for (int r = 0; r < 4; ++r) {
                    const float p2 = __expf(s[sub][nt][r] - SMAX);
                    s[sub][nt][r] = p2;
                    lp[sub][r] += p2;
                }
#pragma unroll
            for (int nt = 0; nt < 4; ++nt)
#pragma unroll
                for (int r = 0; r < 4; ++r)
                    Ps[(wrow + sub * 16 + quad * 4 + r) * 72 + nt * 16 + ll] =
                        (bf16)s[sub][nt][r];
        }

#pragma unroll
        for (int ks = 0; ks < 2; ++ks) {
            bf16x8 a0 = *(const bf16x8*)(Ps + (wrow + ll) * 72 + ks * 32 + quad * 8);
            bf16x8 a1 = *(const bf16x8*)(Ps + (wrow + 16 + ll) * 72 + ks * 32 + quad * 8);
#pragma unroll
            for (int nt = 0; nt < 4; ++nt) {
                const int row = nt * 16 + ll;
                const int pc  = (ks * 4 + quad) ^ (ll & 7);
                bf16x8 b = *(const bf16x8*)(VTs + (row * 8 + pc) * 8);
                o[0][nt] = __builtin_amdgcn_mfma_f32_16x16x32_bf16(a0, b, o[0][nt], 0, 0, 0);
                o[1][nt] = __builtin_amdgcn_mfma_f32_16x16x32_bf16(a1, b, o[1][nt], 0, 0, 0);
            }
        }
    }

#pragma unroll
    for (int sub = 0; sub < 2; ++sub) {
#pragma unroll
        for (int off = 1; off < 16; off <<= 1)
#pragma unroll
            for (int r = 0; r < 4; ++r) lp[sub][r] += __shfl_xor(lp[sub][r], off);

        if (PARTIAL) {
#pragma unroll
            for (int nt = 0; nt < 4; ++nt) {
                const int col = head * DHEAD + nt * 16 + ll;
#pragma unroll
                for (int r = 0; r < 4; ++r) {
                    const int row = q0 + wrow + sub * 16 + quad * 4 + r;
                    opf[((size_t)half * SEQ + row) * DMODEL + col] = o[sub][nt][r];
                }
            }
            if (ll == 0) {
#pragma unroll
                for (int r = 0; r < 4; ++r) {
                    const int row = q0 + wrow + sub * 16 + quad * 4 + r;
                    lsum[((size_t)half * SEQ + row) * NHEADS + head] = lp[sub][r];
                }
            }
        } else {
#pragma unroll
            for (int nt = 0; nt < 4; ++nt) {
                const int d = head * DHEAD + nt * 16 + ll;
#pragma unroll
                for (int r = 0; r < 4; ++r) {
                    const int row = q0 + wrow + sub * 16 + quad * 4 + r;
                    z[(size_t)row * DMODEL + d] = (bf16)(o[sub][nt][r] / lp[sub][r]);
                }
            }
        }
    }
}

// ---------------------------------------------------------------------------
// Merge the two KV-half partials: z = (o0+o1)/(l0+l1). One block per q-row.
// ---------------------------------------------------------------------------
__global__ __launch_bounds__(256)
void combine_halves(const float* __restrict__ opf, const float* __restrict__ lsum,
                    bf16* __restrict__ z) {
    const int row = blockIdx.x;
    const int c   = threadIdx.x * 4;
    const int head = c >> 6;
    const float l = lsum[(size_t)row * NHEADS + head] +
                    lsum[((size_t)SEQ + row) * NHEADS + head];
    const float4 o0 = *(const float4*)(opf + (size_t)row * DMODEL + c);
    const float4 o1 = *(const float4*)(opf + ((size_t)SEQ + row) * DMODEL + c);
    bf16x4 out;
    out[0] = (bf16)((o0.x + o1.x) / l);
    out[1] = (bf16)((o0.y + o1.y) / l);
    out[2] = (bf16)((o0.z + o1.z) / l);
    out[3] = (bf16)((o0.w + o1.w) / l);
    *(bf16x4*)(z + (size_t)row * DMODEL + c) = out;
}

// ---------------------------------------------------------------------------
extern "C" void kernel_launch(void* const* d_in, const int* in_sizes, int n_in,
                              void* d_out, int out_size, void* d_ws, size_t ws_size,
                              hipStream_t stream) {
    const float* x    = (const float*)d_in[0];
    const float* Wqkv = (const float*)d_in[1];
    const float* bqkv = (const float*)d_in[2];
    const float* Wo   = (const float*)d_in[3];
    const float* bo   = (const float*)d_in[4];
    const float* wq   = (const float*)d_in[5];
    const float* wk   = (const float*)d_in[6];
    float* out = (float*)d_out;

    bf16* qkv  = (bf16*)d_ws;                       // [4096][3072]  25.2 MB (v third unused)
    bf16* z    = qkv + (size_t)SEQ * QKV3;          // [4096][1024]   8.4 MB
    bf16* Vt   = z + (size_t)SEQ * DMODEL;          // [16][64][4096] 8.4 MB
    bf16* xb   = Vt + (size_t)NHEADS * DHEAD * SEQ; // [4096][1024]   8.4 MB
    bf16* Wqb  = xb + NX;                           // [3072][1024]   6.3 MB
    bf16* Wob  = Wqb + NW;                          // [1024][1024]   2.1 MB
    bf16* endb = Wob + NO;
    float* opf  = (float*)endb;                     // [2][4096][1024] 33.6 MB
    float* lsum = opf + (size_t)2 * SEQ * DMODEL;   // [2][4096][16]   0.5 MB
    const size_t need = (size_t)((char*)(lsum + (size_t)2 * SEQ * NHEADS) - (char*)d_ws);
    const bool split = ws_size >= need;

    cvt_all<<<dim3((NX + NW + NO) / 2048), 256, 0, stream>>>(x, Wqkv, Wo, xb);

    gemm_qkv<<<dim3(QKV3 / 128, SEQ / 128), 256, 0, stream>>>(
        xb, Wqb, bqkv, wq, wk, qkv, Vt);

    if (split) {
        attn_fwd<true><<<dim3(NHEADS, SEQ / 128, 2), 256, 0, stream>>>(
            qkv, Vt, z, opf, lsum);
        combine_halves<<<dim3(SEQ), 256, 0, stream>>>(opf, lsum, z);
    } else {
        attn_fwd<false><<<dim3(NHEADS, SEQ / 128, 1), 256, 0, stream>>>(
            qkv, Vt, z, nullptr, nullptr);
    }

    gemm_out<<<dim3(DMODEL / 64, SEQ / 128), 256, 0, stream>>>(z, Wob, bo, out);
}